// Round 10
// baseline (196.215 us; speedup 1.0000x reference)
//
#include <hip/hip_runtime.h>
#include <hip/hip_bf16.h>

// B=32, C_IN=64, C_OUT=64, N=1024, T=16
//  kCM: fused kA+kC+kT (round-6 structure, 8-m tile): MFMA y=W_out@x (bf16)
//       -> Yt[b][j=o*16+t][m]; k fp32 during staging; 33.6KB LDS -> 4 blk/CU;
//       XCD-grouped so Yt partial-line writes merge in one L2.
//  kBP: Pbf[b][n][m] = bf16( softmax_m(kq[n]·k[m]) * adj ), XCD-grouped.
//  kD : out = P@Yt (verified r7/r9): 256x256, BK=64, 4-phase, src-swizzled
//       linear LDS, global_load_lds(16B), counted vmcnt(8), setprio, XCD-grouped.

typedef float  f32x4 __attribute__((ext_vector_type(4)));
typedef short  s16x8 __attribute__((ext_vector_type(8)));
typedef unsigned short u16x8 __attribute__((ext_vector_type(8)));

#define GLOAD_LDS16(g, l) __builtin_amdgcn_global_load_lds(                    \
    (const __attribute__((address_space(1))) void*)(g),                        \
    (__attribute__((address_space(3))) void*)(l), 16, 0, 0)

static __device__ __forceinline__ unsigned short f2bf(float f) {
    __hip_bfloat16 h = __float2bfloat16(f);
    return *reinterpret_cast<unsigned short*>(&h);
}

// ---------------- kCM: fused y-GEMM + transpose + k/kq (8-m tile) ----------
// block = (b, 8 m = 128 j), 256 threads, 4 waves.
// LDS: [0,18432) xtb u16[64][132] (16896) overlapped by Ys u16[128][72];
// Wb u16[64][72] @18432; al @27648; wl[16][17] @27904; kl[128] @28992;
// kred[8][128] @29504; total 33600 B -> 4 blocks/CU.
__global__ __launch_bounds__(256, 4) void kCM(const float* __restrict__ x,
                                              const float* __restrict__ Wout,
                                              const float* __restrict__ alpha,
                                              const float* __restrict__ Watt,
                                              unsigned short* __restrict__ Yt,
                                              float* __restrict__ kk_,
                                              float* __restrict__ kq_) {
    extern __shared__ char sm[];
    unsigned short* xtb = (unsigned short*)sm;            // [64][132]
    unsigned short* Ys  = (unsigned short*)sm;            // [128][72] (xtb dead)
    unsigned short* Wb  = (unsigned short*)(sm + 18432);  // [64][72]
    float* al   = (float*)(sm + 27648);
    float* wl   = (float*)(sm + 27904);                   // [16][17]
    float* kl   = (float*)(sm + 28992);                   // [128]
    float* kred = (float*)(sm + 29504);                   // [8][128]
    int tid = threadIdx.x;
    // XCD-grouped bijective mapping (4096 % 8 == 0)
    int bid = blockIdx.x;
    int wg  = (bid & 7) * 512 + (bid >> 3);
    int b   = wg >> 7;
    int mc  = wg & 127;
    int j0 = mc << 7;
    int m0 = mc << 3;
    if (tid < 64) al[tid] = alpha[tid];
    wl[(tid >> 4) * 17 + (tid & 15)] = Watt[tid];
    #pragma unroll
    for (int it = 0; it < 16; ++it) {
        int idx = it * 256 + tid;
        Wb[(idx >> 6) * 72 + (idx & 63)] = f2bf(Wout[idx]);
    }
    __syncthreads();
    // stage x (bf16) + fp32 k-partials on the fly
    int cg = tid >> 5, q = tid & 31;
    const float* xb = x + (size_t)b * (64 * 16384) + j0;
    float kp[4] = {0.f, 0.f, 0.f, 0.f};
    #pragma unroll
    for (int it = 0; it < 8; ++it) {
        int c = it * 8 + cg;
        float4 v = *(const float4*)(xb + (size_t)c * 16384 + q * 4);
        float a = al[c];
        kp[0] = fmaf(a, v.x, kp[0]);
        kp[1] = fmaf(a, v.y, kp[1]);
        kp[2] = fmaf(a, v.z, kp[2]);
        kp[3] = fmaf(a, v.w, kp[3]);
        ushort4 pk = make_ushort4(f2bf(v.x), f2bf(v.y), f2bf(v.z), f2bf(v.w));
        *(ushort4*)&xtb[c * 132 + q * 4] = pk;
    }
    *(float4*)&kred[cg * 128 + q * 4] = make_float4(kp[0], kp[1], kp[2], kp[3]);
    __syncthreads();   // xtb + kred ready
    // frags -> regs; k reduce
    int w = tid >> 6, lane = tid & 63;
    int l15 = lane & 15, lhi = lane >> 4;
    int jw = w << 5;
    s16x8 af[4][2], bfv[2][2];
    #pragma unroll
    for (int fro = 0; fro < 4; ++fro)
        #pragma unroll
        for (int ks = 0; ks < 2; ++ks)
            af[fro][ks] = *(const s16x8*)&Wb[(fro * 16 + l15) * 72 + ks * 32 + lhi * 8];
    #pragma unroll
    for (int fc = 0; fc < 2; ++fc)
        #pragma unroll
        for (int ks = 0; ks < 2; ++ks) {
            int jcol = jw + fc * 16 + l15;
            int cb = ks * 32 + lhi * 8;
            s16x8 t;
            #pragma unroll
            for (int e = 0; e < 8; ++e)
                t[e] = (short)xtb[(cb + e) * 132 + jcol];
            bfv[fc][ks] = t;
        }
    if (tid < 128) {
        float kv = 0.f;
        #pragma unroll
        for (int g8 = 0; g8 < 8; ++g8) kv += kred[g8 * 128 + tid];
        kl[tid] = kv;
        kk_[(size_t)b * 16384 + j0 + tid] = kv;
    }
    __syncthreads();   // xtb dead; kl ready
    // MFMA y = W @ x
    f32x4 acc[4][2] = {};
    #pragma unroll
    for (int ks = 0; ks < 2; ++ks)
        #pragma unroll
        for (int fc = 0; fc < 2; ++fc)
            #pragma unroll
            for (int fro = 0; fro < 4; ++fro)
                acc[fro][fc] = __builtin_amdgcn_mfma_f32_16x16x32_bf16(
                    af[fro][ks], bfv[fc][ks], acc[fro][fc], 0, 0, 0);
    // kq
    if (tid < 128) {
        int ml = tid >> 4, tq = tid & 15;
        float qv = 0.f;
        #pragma unroll
        for (int s = 0; s < 16; ++s) qv = fmaf(kl[ml * 16 + s], wl[s * 17 + tq], qv);
        kq_[(size_t)b * 16384 + j0 + tid] = qv;
    }
    // C frags -> Ys[j_local][o]
    #pragma unroll
    for (int fro = 0; fro < 4; ++fro)
        #pragma unroll
        for (int fc = 0; fc < 2; ++fc) {
            int jl = jw + fc * 16 + l15;
            int o0 = fro * 16 + lhi * 4;
            ushort4 pk = make_ushort4(f2bf(acc[fro][fc][0]), f2bf(acc[fro][fc][1]),
                                      f2bf(acc[fro][fc][2]), f2bf(acc[fro][fc][3]));
            *(ushort4*)&Ys[jl * 72 + o0] = pk;
        }
    __syncthreads();
    // Yt[b][r=o*16+t][m0..m0+8) = Ys[m_local*16+t][o]
    #pragma unroll
    for (int it = 0; it < 4; ++it) {
        int r = it * 256 + tid;
        int o = r >> 4, t = r & 15;
        u16x8 v0;
        #pragma unroll
        for (int q8 = 0; q8 < 8; ++q8) v0[q8] = Ys[(q8 * 16 + t) * 72 + o];
        unsigned short* dst = Yt + (((size_t)b << 10) + r) * 1024 + m0;
        *(u16x8*)dst = v0;
    }
}

// ---------------- kBP: P panel (XCD-grouped) ----------------
__global__ __launch_bounds__(256) void kBP(const float* __restrict__ kk_,
                                           const float* __restrict__ kq_,
                                           const float* __restrict__ adj,
                                           unsigned short* __restrict__ Pbf) {
    int tid = threadIdx.x;
    int bid = blockIdx.x;
    int wg  = (bid & 7) * 1024 + (bid >> 3);   // 8192 % 8 == 0, bijective
    int b  = wg >> 8;
    int n0 = (wg & 255) * 4;
    __shared__ float kql[4][16];
    __shared__ float redm[4][4], reds[4][4];
    if (tid < 64)
        kql[tid >> 4][tid & 15] =
            kq_[((size_t)b * 1024 + n0 + (tid >> 4)) * 16 + (tid & 15)];
    __syncthreads();
    const float* kb = kk_ + (size_t)b * 16384;
    float kf[4][16];
    #pragma unroll
    for (int u = 0; u < 4; ++u) {
        const float* p = &kb[(size_t)(u * 256 + tid) * 16];
        #pragma unroll
        for (int s = 0; s < 16; ++s) kf[u][s] = p[s];
    }
    float sc[4][4];
    #pragma unroll
    for (int r = 0; r < 4; ++r)
        #pragma unroll
        for (int u = 0; u < 4; ++u) {
            float a = 0.f;
            #pragma unroll
            for (int s = 0; s < 16; ++s) a = fmaf(kql[r][s], kf[u][s], a);
            sc[r][u] = a;
        }
    float mx[4];
    #pragma unroll
    for (int r = 0; r < 4; ++r)
        mx[r] = fmaxf(fmaxf(sc[r][0], sc[r][1]), fmaxf(sc[r][2], sc[r][3]));
    #pragma unroll
    for (int off = 32; off; off >>= 1)
        #pragma unroll
        for (int r = 0; r < 4; ++r) mx[r] = fmaxf(mx[r], __shfl_xor(mx[r], off));
    int w = tid >> 6;
    if ((tid & 63) == 0)
        #pragma unroll
        for (int r = 0; r < 4; ++r) redm[w][r] = mx[r];
    __syncthreads();
    #pragma unroll
    for (int r = 0; r < 4; ++r)
        mx[r] = fmaxf(fmaxf(redm[0][r], redm[1][r]), fmaxf(redm[2][r], redm[3][r]));
    float e[4][4], se[4];
    #pragma unroll
    for (int r = 0; r < 4; ++r) {
        float s = 0.f;
        #pragma unroll
        for (int u = 0; u < 4; ++u) { e[r][u] = __expf(sc[r][u] - mx[r]); s += e[r][u]; }
        se[r] = s;
    }
    #pragma unroll
    for (int off = 32; off; off >>= 1)
        #pragma unroll
        for (int r = 0; r < 4; ++r) se[r] += __shfl_xor(se[r], off);
    if ((tid & 63) == 0)
        #pragma unroll
        for (int r = 0; r < 4; ++r) reds[w][r] = se[r];
    __syncthreads();
    float rrs[4];
    #pragma unroll
    for (int r = 0; r < 4; ++r)
        rrs[r] = 1.f / (reds[0][r] + reds[1][r] + reds[2][r] + reds[3][r]);
    #pragma unroll
    for (int r = 0; r < 4; ++r)
        #pragma unroll
        for (int u = 0; u < 4; ++u) {
            size_t m = (size_t)u * 256 + tid;
            float av = adj[(size_t)(n0 + r) * 1024 + m];
            Pbf[((size_t)b * 1024 + n0 + r) * 1024 + m] = f2bf(e[r][u] * rrs[r] * av);
        }
}

// ---------------- kD (verified r7/r9): counted-vmcnt pipeline ----------------
static __device__ __forceinline__ void stage_tile(const unsigned short* Pb,
                                                  const unsigned short* Yb,
                                                  unsigned short* lds, int buf,
                                                  int kt, int ww, int l) {
    int r8  = (l >> 3) & 7;
    int glc = ((l & 7) ^ r8) << 3;       // swizzled source k-offset (ushorts)
    int k0  = kt << 6;
    unsigned short* base = lds + buf * 32768;
    #pragma unroll
    for (int s = 0; s < 4; ++s) {
        int row  = s * 64 + ww * 8;                       // wave-uniform
        size_t g = ((size_t)(row + r8) << 10) + k0 + glc; // per-lane
        GLOAD_LDS16(Pb + g, base + row * 64);
        GLOAD_LDS16(Yb + g, base + 16384 + row * 64);
    }
}

static __device__ __forceinline__ s16x8 frag_ld(const unsigned short* base,
                                                int R, int kc, int l7) {
    return *(const s16x8*)(base + R * 64 + ((kc ^ l7) << 3));
}

__global__ __launch_bounds__(512, 2) void kD(const unsigned short* __restrict__ P,
                                             const unsigned short* __restrict__ Yt,
                                             float* __restrict__ out) {
    extern __shared__ unsigned short lds[];   // 2 bufs x 64 KB = 128 KiB
    int bid = blockIdx.x;
    int wg  = (bid & 7) * 64 + (bid >> 3);    // XCD-grouped (512 % 8 == 0)
    int b   = wg >> 4;
    int rem = wg & 15;
    int n0  = (rem & 3) << 8;
    int j0  = (rem >> 2) << 8;
    int tid = threadIdx.x;
    int l = tid & 63, ww = tid >> 6;
    int wr = ww >> 2, wc = ww & 3;       // 2 x 4 wave grid
    int l15 = l & 15, lhi = l >> 4, l7 = l & 7;
    const unsigned short* Pb = P  + ((size_t)b << 20) + ((size_t)n0 << 10);
    const unsigned short* Yb = Yt + ((size_t)b << 20) + ((size_t)j0 << 10);

    f32x4 acc[8][4] = {};
    stage_tile(Pb, Yb, lds, 0, 0, ww, l);    // tile 0 -> buf 0

    for (int kt = 0; kt < 16; ++kt) {
        int cur = kt & 1;
        const unsigned short* Ab = lds + cur * 32768;
        const unsigned short* Bb = Ab + 16384;
        // issue next tile's stage BEFORE the wait, then counted wait:
        // vmcnt(8) drains stage(kt) while stage(kt+1) stays in flight.
        if (kt < 15) {
            stage_tile(Pb, Yb, lds, cur ^ 1, kt + 1, ww, l);
            asm volatile("s_waitcnt vmcnt(8)" ::: "memory");
        } else {
            asm volatile("s_waitcnt vmcnt(0)" ::: "memory");
        }
        __builtin_amdgcn_s_barrier();        // tile kt fully resident
        s16x8 bf[4][2];
        #pragma unroll
        for (int q = 0; q < 4; ++q) {
            if (q == 0) {
                #pragma unroll
                for (int nj = 0; nj < 4; ++nj)
                    #pragma unroll
                    for (int ks = 0; ks < 2; ++ks)
                        bf[nj][ks] = frag_ld(Bb, wc * 64 + nj * 16 + l15,
                                             ks * 4 + lhi, l7);
            }
            s16x8 af[2][2];
            #pragma unroll
            for (int mi = 0; mi < 2; ++mi)
                #pragma unroll
                for (int ks = 0; ks < 2; ++ks)
                    af[mi][ks] = frag_ld(Ab, wr * 128 + (q * 2 + mi) * 16 + l15,
                                         ks * 4 + lhi, l7);
            __builtin_amdgcn_s_barrier();
            asm volatile("s_waitcnt lgkmcnt(0)" ::: "memory");
            __builtin_amdgcn_sched_barrier(0);
            __builtin_amdgcn_s_setprio(1);
            #pragma unroll
            for (int mi = 0; mi < 2; ++mi)
                #pragma unroll
                for (int nj = 0; nj < 4; ++nj)
                    #pragma unroll
                    for (int ks = 0; ks < 2; ++ks)
                        acc[q * 2 + mi][nj] = __builtin_amdgcn_mfma_f32_16x16x32_bf16(
                            af[mi][ks], bf[nj][ks], acc[q * 2 + mi][nj], 0, 0, 0);
            __builtin_amdgcn_s_setprio(0);
            if (q < 3) __builtin_amdgcn_s_barrier();
        }
        __builtin_amdgcn_s_barrier();        // tile end (reads retired; no drain)
    }

    #pragma unroll
    for (int mi = 0; mi < 8; ++mi)
        #pragma unroll
        for (int nj = 0; nj < 4; ++nj) {
            int o  = (j0 >> 4) + wc * 4 + nj;
            int nb = n0 + wr * 128 + mi * 16 + lhi * 4;
            float* op = out + ((size_t)(b * 64 + o) << 14) + (size_t)nb * 16 + l15;
            #pragma unroll
            for (int q = 0; q < 4; ++q) op[q * 16] = acc[mi][nj][q];
        }
}

extern "C" void kernel_launch(void* const* d_in, const int* in_sizes, int n_in,
                              void* d_out, int out_size, void* d_ws, size_t ws_size,
                              hipStream_t stream) {
    const float* x     = (const float*)d_in[0];
    const float* adj   = (const float*)d_in[1];
    const float* alpha = (const float*)d_in[2];
    const float* Watt  = (const float*)d_in[3];
    const float* Wout  = (const float*)d_in[4];
    float* out = (float*)d_out;

    char* ws = (char*)d_ws;
    float* k  = (float*)ws;                                            // 2 MB
    float* kq = (float*)(ws + 2097152);                                // 2 MB
    unsigned short* Pbf = (unsigned short*)(ws + 4194304);             // 64 MB
    unsigned short* Yt  = (unsigned short*)(ws + 4194304 + 67108864);  // 64 MB

    kCM<<<4096, 256, 33600, stream>>>(x, Wout, alpha, Watt, Yt, k, kq);
    kBP<<<8192, 256, 0, stream>>>(k, kq, adj, Pbf);
    kD <<<512, 512, 131072, stream>>>(Pbf, Yt, out);
}

// Round 11
// 194.747 us; speedup vs baseline: 1.0075x; 1.0075x over previous
//
#include <hip/hip_runtime.h>
#include <hip/hip_bf16.h>

// B=32, C_IN=64, C_OUT=64, N=1024, T=16
//  kCM: fused kA+kC+kT (r10 structure): MFMA y=W_out@x (bf16) ->
//       Yt CHUNKED layout Yt[b][mc][r][8] (mc=m>>3, r=o*16+t) so each block
//       writes one contiguous 16KB chunk (no partial-line scatter).
//  kBP: Pbf[b][n][m] = bf16( softmax_m(kq[n]·k[m]) * adj ), XCD-grouped.
//  kD : out = P@Yt (verified r7/r9 loop, B-source address adapted to chunk
//       layout — LDS content/frags/sync byte-identical).

typedef float  f32x4 __attribute__((ext_vector_type(4)));
typedef short  s16x8 __attribute__((ext_vector_type(8)));
typedef unsigned short u16x8 __attribute__((ext_vector_type(8)));

#define GLOAD_LDS16(g, l) __builtin_amdgcn_global_load_lds(                    \
    (const __attribute__((address_space(1))) void*)(g),                        \
    (__attribute__((address_space(3))) void*)(l), 16, 0, 0)

static __device__ __forceinline__ unsigned short f2bf(float f) {
    __hip_bfloat16 h = __float2bfloat16(f);
    return *reinterpret_cast<unsigned short*>(&h);
}

// ---------------- kCM: fused y-GEMM + transpose + k/kq (8-m tile) ----------
// block = (b, 8 m = 128 j), 256 threads, 4 waves. LDS total 33600 B.
__global__ __launch_bounds__(256, 4) void kCM(const float* __restrict__ x,
                                              const float* __restrict__ Wout,
                                              const float* __restrict__ alpha,
                                              const float* __restrict__ Watt,
                                              unsigned short* __restrict__ Yt,
                                              float* __restrict__ kk_,
                                              float* __restrict__ kq_) {
    extern __shared__ char sm[];
    unsigned short* xtb = (unsigned short*)sm;            // [64][132]
    unsigned short* Ys  = (unsigned short*)sm;            // [128][72] (xtb dead)
    unsigned short* Wb  = (unsigned short*)(sm + 18432);  // [64][72]
    float* al   = (float*)(sm + 27648);
    float* wl   = (float*)(sm + 27904);                   // [16][17]
    float* kl   = (float*)(sm + 28992);                   // [128]
    float* kred = (float*)(sm + 29504);                   // [8][128]
    int tid = threadIdx.x;
    // XCD-grouped bijective mapping (4096 % 8 == 0)
    int bid = blockIdx.x;
    int wg  = (bid & 7) * 512 + (bid >> 3);
    int b   = wg >> 7;
    int mc  = wg & 127;
    int j0 = mc << 7;
    if (tid < 64) al[tid] = alpha[tid];
    wl[(tid >> 4) * 17 + (tid & 15)] = Watt[tid];
    #pragma unroll
    for (int it = 0; it < 16; ++it) {
        int idx = it * 256 + tid;
        Wb[(idx >> 6) * 72 + (idx & 63)] = f2bf(Wout[idx]);
    }
    __syncthreads();
    // stage x (bf16) + fp32 k-partials on the fly
    int cg = tid >> 5, q = tid & 31;
    const float* xb = x + (size_t)b * (64 * 16384) + j0;
    float kp[4] = {0.f, 0.f, 0.f, 0.f};
    #pragma unroll
    for (int it = 0; it < 8; ++it) {
        int c = it * 8 + cg;
        float4 v = *(const float4*)(xb + (size_t)c * 16384 + q * 4);
        float a = al[c];
        kp[0] = fmaf(a, v.x, kp[0]);
        kp[1] = fmaf(a, v.y, kp[1]);
        kp[2] = fmaf(a, v.z, kp[2]);
        kp[3] = fmaf(a, v.w, kp[3]);
        ushort4 pk = make_ushort4(f2bf(v.x), f2bf(v.y), f2bf(v.z), f2bf(v.w));
        *(ushort4*)&xtb[c * 132 + q * 4] = pk;
    }
    *(float4*)&kred[cg * 128 + q * 4] = make_float4(kp[0], kp[1], kp[2], kp[3]);
    __syncthreads();   // xtb + kred ready
    // frags -> regs; k reduce
    int w = tid >> 6, lane = tid & 63;
    int l15 = lane & 15, lhi = lane >> 4;
    int jw = w << 5;
    s16x8 af[4][2], bfv[2][2];
    #pragma unroll
    for (int fro = 0; fro < 4; ++fro)
        #pragma unroll
        for (int ks = 0; ks < 2; ++ks)
            af[fro][ks] = *(const s16x8*)&Wb[(fro * 16 + l15) * 72 + ks * 32 + lhi * 8];
    #pragma unroll
    for (int fc = 0; fc < 2; ++fc)
        #pragma unroll
        for (int ks = 0; ks < 2; ++ks) {
            int jcol = jw + fc * 16 + l15;
            int cb = ks * 32 + lhi * 8;
            s16x8 t;
            #pragma unroll
            for (int e = 0; e < 8; ++e)
                t[e] = (short)xtb[(cb + e) * 132 + jcol];
            bfv[fc][ks] = t;
        }
    if (tid < 128) {
        float kv = 0.f;
        #pragma unroll
        for (int g8 = 0; g8 < 8; ++g8) kv += kred[g8 * 128 + tid];
        kl[tid] = kv;
        kk_[(size_t)b * 16384 + j0 + tid] = kv;
    }
    __syncthreads();   // xtb dead; kl ready
    // MFMA y = W @ x
    f32x4 acc[4][2] = {};
    #pragma unroll
    for (int ks = 0; ks < 2; ++ks)
        #pragma unroll
        for (int fc = 0; fc < 2; ++fc)
            #pragma unroll
            for (int fro = 0; fro < 4; ++fro)
                acc[fro][fc] = __builtin_amdgcn_mfma_f32_16x16x32_bf16(
                    af[fro][ks], bfv[fc][ks], acc[fro][fc], 0, 0, 0);
    // kq
    if (tid < 128) {
        int ml = tid >> 4, tq = tid & 15;
        float qv = 0.f;
        #pragma unroll
        for (int s = 0; s < 16; ++s) qv = fmaf(kl[ml * 16 + s], wl[s * 17 + tq], qv);
        kq_[(size_t)b * 16384 + j0 + tid] = qv;
    }
    // C frags -> Ys[j_local][o]
    #pragma unroll
    for (int fro = 0; fro < 4; ++fro)
        #pragma unroll
        for (int fc = 0; fc < 2; ++fc) {
            int jl = jw + fc * 16 + l15;
            int o0 = fro * 16 + lhi * 4;
            ushort4 pk = make_ushort4(f2bf(acc[fro][fc][0]), f2bf(acc[fro][fc][1]),
                                      f2bf(acc[fro][fc][2]), f2bf(acc[fro][fc][3]));
            *(ushort4*)&Ys[jl * 72 + o0] = pk;
        }
    __syncthreads();
    // CHUNKED write: Yt[b][mc][r][8] — one contiguous 16KB block per CTA.
    unsigned short* dstb = Yt + ((size_t)b << 20) + (size_t)mc * 8192;
    #pragma unroll
    for (int it = 0; it < 4; ++it) {
        int r = it * 256 + tid;
        int o = r >> 4, t = r & 15;
        u16x8 v0;
        #pragma unroll
        for (int q8 = 0; q8 < 8; ++q8) v0[q8] = Ys[(q8 * 16 + t) * 72 + o];
        *(u16x8*)(dstb + (size_t)r * 8) = v0;
    }
}

// ---------------- kBP: P panel (XCD-grouped, unchanged) ----------------
__global__ __launch_bounds__(256) void kBP(const float* __restrict__ kk_,
                                           const float* __restrict__ kq_,
                                           const float* __restrict__ adj,
                                           unsigned short* __restrict__ Pbf) {
    int tid = threadIdx.x;
    int bid = blockIdx.x;
    int wg  = (bid & 7) * 1024 + (bid >> 3);   // 8192 % 8 == 0, bijective
    int b  = wg >> 8;
    int n0 = (wg & 255) * 4;
    __shared__ float kql[4][16];
    __shared__ float redm[4][4], reds[4][4];
    if (tid < 64)
        kql[tid >> 4][tid & 15] =
            kq_[((size_t)b * 1024 + n0 + (tid >> 4)) * 16 + (tid & 15)];
    __syncthreads();
    const float* kb = kk_ + (size_t)b * 16384;
    float kf[4][16];
    #pragma unroll
    for (int u = 0; u < 4; ++u) {
        const float* p = &kb[(size_t)(u * 256 + tid) * 16];
        #pragma unroll
        for (int s = 0; s < 16; ++s) kf[u][s] = p[s];
    }
    float sc[4][4];
    #pragma unroll
    for (int r = 0; r < 4; ++r)
        #pragma unroll
        for (int u = 0; u < 4; ++u) {
            float a = 0.f;
            #pragma unroll
            for (int s = 0; s < 16; ++s) a = fmaf(kql[r][s], kf[u][s], a);
            sc[r][u] = a;
        }
    float mx[4];
    #pragma unroll
    for (int r = 0; r < 4; ++r)
        mx[r] = fmaxf(fmaxf(sc[r][0], sc[r][1]), fmaxf(sc[r][2], sc[r][3]));
    #pragma unroll
    for (int off = 32; off; off >>= 1)
        #pragma unroll
        for (int r = 0; r < 4; ++r) mx[r] = fmaxf(mx[r], __shfl_xor(mx[r], off));
    int w = tid >> 6;
    if ((tid & 63) == 0)
        #pragma unroll
        for (int r = 0; r < 4; ++r) redm[w][r] = mx[r];
    __syncthreads();
    #pragma unroll
    for (int r = 0; r < 4; ++r)
        mx[r] = fmaxf(fmaxf(redm[0][r], redm[1][r]), fmaxf(redm[2][r], redm[3][r]));
    float e[4][4], se[4];
    #pragma unroll
    for (int r = 0; r < 4; ++r) {
        float s = 0.f;
        #pragma unroll
        for (int u = 0; u < 4; ++u) { e[r][u] = __expf(sc[r][u] - mx[r]); s += e[r][u]; }
        se[r] = s;
    }
    #pragma unroll
    for (int off = 32; off; off >>= 1)
        #pragma unroll
        for (int r = 0; r < 4; ++r) se[r] += __shfl_xor(se[r], off);
    if ((tid & 63) == 0)
        #pragma unroll
        for (int r = 0; r < 4; ++r) reds[w][r] = se[r];
    __syncthreads();
    float rrs[4];
    #pragma unroll
    for (int r = 0; r < 4; ++r)
        rrs[r] = 1.f / (reds[0][r] + reds[1][r] + reds[2][r] + reds[3][r]);
    #pragma unroll
    for (int r = 0; r < 4; ++r)
        #pragma unroll
        for (int u = 0; u < 4; ++u) {
            size_t m = (size_t)u * 256 + tid;
            float av = adj[(size_t)(n0 + r) * 1024 + m];
            Pbf[((size_t)b * 1024 + n0 + r) * 1024 + m] = f2bf(e[r][u] * rrs[r] * av);
        }
}

// ---------------- kD (verified loop; B source = chunk layout) ----------------
static __device__ __forceinline__ void stage_tile(const unsigned short* Pb,
                                                  const unsigned short* Yb,
                                                  unsigned short* lds, int buf,
                                                  int kt, int ww, int l) {
    int r8  = (l >> 3) & 7;
    int cs  = (l & 7) ^ r8;              // swizzled source chunk index
    int glc = cs << 3;                   // A: k-offset (ushorts)
    int k0  = kt << 6;
    unsigned short* base = lds + buf * 32768;
    #pragma unroll
    for (int s = 0; s < 4; ++s) {
        int row = s * 64 + ww * 8;                        // wave-uniform
        // A (P): row-major [n][m]
        size_t ga = ((size_t)(row + r8) << 10) + k0 + glc;
        GLOAD_LDS16(Pb + ga, base + row * 64);
        // B (Yt): chunk layout [mc][r][8]; chunk mc = kt*8 + cs at r = row+r8
        size_t gb = (size_t)(kt * 8 + cs) * 8192 + (size_t)(row + r8) * 8;
        GLOAD_LDS16(Yb + gb, base + 16384 + row * 64);
    }
}

static __device__ __forceinline__ s16x8 frag_ld(const unsigned short* base,
                                                int R, int kc, int l7) {
    return *(const s16x8*)(base + R * 64 + ((kc ^ l7) << 3));
}

__global__ __launch_bounds__(512, 2) void kD(const unsigned short* __restrict__ P,
                                             const unsigned short* __restrict__ Yt,
                                             float* __restrict__ out) {
    extern __shared__ unsigned short lds[];   // 2 bufs x 64 KB = 128 KiB
    int bid = blockIdx.x;
    int wg  = (bid & 7) * 64 + (bid >> 3);    // XCD-grouped (512 % 8 == 0)
    int b   = wg >> 4;
    int rem = wg & 15;
    int n0  = (rem & 3) << 8;
    int j0  = (rem >> 2) << 8;
    int tid = threadIdx.x;
    int l = tid & 63, ww = tid >> 6;
    int wr = ww >> 2, wc = ww & 3;       // 2 x 4 wave grid
    int l15 = l & 15, lhi = l >> 4, l7 = l & 7;
    const unsigned short* Pb = P  + ((size_t)b << 20) + ((size_t)n0 << 10);
    const unsigned short* Yb = Yt + ((size_t)b << 20) + (size_t)j0 * 8;  // r-offset

    f32x4 acc[8][4] = {};
    stage_tile(Pb, Yb, lds, 0, 0, ww, l);    // tile 0 -> buf 0

    for (int kt = 0; kt < 16; ++kt) {
        int cur = kt & 1;
        const unsigned short* Ab = lds + cur * 32768;
        const unsigned short* Bb = Ab + 16384;
        // counted wait: vmcnt(8) drains stage(kt), stage(kt+1) stays in flight
        if (kt < 15) {
            stage_tile(Pb, Yb, lds, cur ^ 1, kt + 1, ww, l);
            asm volatile("s_waitcnt vmcnt(8)" ::: "memory");
        } else {
            asm volatile("s_waitcnt vmcnt(0)" ::: "memory");
        }
        __builtin_amdgcn_s_barrier();        // tile kt fully resident
        s16x8 bf[4][2];
        #pragma unroll
        for (int q = 0; q < 4; ++q) {
            if (q == 0) {
                #pragma unroll
                for (int nj = 0; nj < 4; ++nj)
                    #pragma unroll
                    for (int ks = 0; ks < 2; ++ks)
                        bf[nj][ks] = frag_ld(Bb, wc * 64 + nj * 16 + l15,
                                             ks * 4 + lhi, l7);
            }
            s16x8 af[2][2];
            #pragma unroll
            for (int mi = 0; mi < 2; ++mi)
                #pragma unroll
                for (int ks = 0; ks < 2; ++ks)
                    af[mi][ks] = frag_ld(Ab, wr * 128 + (q * 2 + mi) * 16 + l15,
                                         ks * 4 + lhi, l7);
            __builtin_amdgcn_s_barrier();
            asm volatile("s_waitcnt lgkmcnt(0)" ::: "memory");
            __builtin_amdgcn_sched_barrier(0);
            __builtin_amdgcn_s_setprio(1);
            #pragma unroll
            for (int mi = 0; mi < 2; ++mi)
                #pragma unroll
                for (int nj = 0; nj < 4; ++nj)
                    #pragma unroll
                    for (int ks = 0; ks < 2; ++ks)
                        acc[q * 2 + mi][nj] = __builtin_amdgcn_mfma_f32_16x16x32_bf16(
                            af[mi][ks], bf[nj][ks], acc[q * 2 + mi][nj], 0, 0, 0);
            __builtin_amdgcn_s_setprio(0);
            if (q < 3) __builtin_amdgcn_s_barrier();
        }
        __builtin_amdgcn_s_barrier();        // tile end (reads retired; no drain)
    }

    #pragma unroll
    for (int mi = 0; mi < 8; ++mi)
        #pragma unroll
        for (int nj = 0; nj < 4; ++nj) {
            int o  = (j0 >> 4) + wc * 4 + nj;
            int nb = n0 + wr * 128 + mi * 16 + lhi * 4;
            float* op = out + ((size_t)(b * 64 + o) << 14) + (size_t)nb * 16 + l15;
            #pragma unroll
            for (int q = 0; q < 4; ++q) op[q * 16] = acc[mi][nj][q];
        }
}

extern "C" void kernel_launch(void* const* d_in, const int* in_sizes, int n_in,
                              void* d_out, int out_size, void* d_ws, size_t ws_size,
                              hipStream_t stream) {
    const float* x     = (const float*)d_in[0];
    const float* adj   = (const float*)d_in[1];
    const float* alpha = (const float*)d_in[2];
    const float* Watt  = (const float*)d_in[3];
    const float* Wout  = (const float*)d_in[4];
    float* out = (float*)d_out;

    char* ws = (char*)d_ws;
    float* k  = (float*)ws;                                            // 2 MB
    float* kq = (float*)(ws + 2097152);                                // 2 MB
    unsigned short* Pbf = (unsigned short*)(ws + 4194304);             // 64 MB
    unsigned short* Yt  = (unsigned short*)(ws + 4194304 + 67108864);  // 64 MB

    kCM<<<4096, 256, 33600, stream>>>(x, Wout, alpha, Watt, Yt, k, kq);
    kBP<<<8192, 256, 0, stream>>>(k, kq, adj, Pbf);
    kD <<<512, 512, 131072, stream>>>(Pbf, Yt, out);
}

// Round 12
// 193.982 us; speedup vs baseline: 1.0115x; 1.0039x over previous
//
#include <hip/hip_runtime.h>
#include <hip/hip_bf16.h>

// B=32, C_IN=64, C_OUT=64, N=1024, T=16
//  kCM: fused kA+kC+kT (r11 verified): MFMA y=W_out@x (bf16) -> Yt chunked
//       Yt[b][mc][r][8]; k fp32 during staging; 33.6KB LDS, XCD-grouped.
//  kBP: Pbf[b][n][m] = bf16( softmax_m(kq[n]·k[m]) * adj ), XCD-grouped.
//  kD : out = P@Yt. r11 loop + ONE change: A-frag reads pipelined one phase
//       ahead with counted lgkmcnt(4) (LDS pipe overlaps MFMA pipe).

typedef float  f32x4 __attribute__((ext_vector_type(4)));
typedef short  s16x8 __attribute__((ext_vector_type(8)));
typedef unsigned short u16x8 __attribute__((ext_vector_type(8)));

#define GLOAD_LDS16(g, l) __builtin_amdgcn_global_load_lds(                    \
    (const __attribute__((address_space(1))) void*)(g),                        \
    (__attribute__((address_space(3))) void*)(l), 16, 0, 0)

static __device__ __forceinline__ unsigned short f2bf(float f) {
    __hip_bfloat16 h = __float2bfloat16(f);
    return *reinterpret_cast<unsigned short*>(&h);
}

// ---------------- kCM (r11 verified) ----------------
__global__ __launch_bounds__(256, 4) void kCM(const float* __restrict__ x,
                                              const float* __restrict__ Wout,
                                              const float* __restrict__ alpha,
                                              const float* __restrict__ Watt,
                                              unsigned short* __restrict__ Yt,
                                              float* __restrict__ kk_,
                                              float* __restrict__ kq_) {
    extern __shared__ char sm[];
    unsigned short* xtb = (unsigned short*)sm;            // [64][132]
    unsigned short* Ys  = (unsigned short*)sm;            // [128][72] (xtb dead)
    unsigned short* Wb  = (unsigned short*)(sm + 18432);  // [64][72]
    float* al   = (float*)(sm + 27648);
    float* wl   = (float*)(sm + 27904);                   // [16][17]
    float* kl   = (float*)(sm + 28992);                   // [128]
    float* kred = (float*)(sm + 29504);                   // [8][128]
    int tid = threadIdx.x;
    int bid = blockIdx.x;
    int wg  = (bid & 7) * 512 + (bid >> 3);               // XCD-grouped
    int b   = wg >> 7;
    int mc  = wg & 127;
    int j0 = mc << 7;
    if (tid < 64) al[tid] = alpha[tid];
    wl[(tid >> 4) * 17 + (tid & 15)] = Watt[tid];
    #pragma unroll
    for (int it = 0; it < 16; ++it) {
        int idx = it * 256 + tid;
        Wb[(idx >> 6) * 72 + (idx & 63)] = f2bf(Wout[idx]);
    }
    __syncthreads();
    int cg = tid >> 5, q = tid & 31;
    const float* xb = x + (size_t)b * (64 * 16384) + j0;
    float kp[4] = {0.f, 0.f, 0.f, 0.f};
    #pragma unroll
    for (int it = 0; it < 8; ++it) {
        int c = it * 8 + cg;
        float4 v = *(const float4*)(xb + (size_t)c * 16384 + q * 4);
        float a = al[c];
        kp[0] = fmaf(a, v.x, kp[0]);
        kp[1] = fmaf(a, v.y, kp[1]);
        kp[2] = fmaf(a, v.z, kp[2]);
        kp[3] = fmaf(a, v.w, kp[3]);
        ushort4 pk = make_ushort4(f2bf(v.x), f2bf(v.y), f2bf(v.z), f2bf(v.w));
        *(ushort4*)&xtb[c * 132 + q * 4] = pk;
    }
    *(float4*)&kred[cg * 128 + q * 4] = make_float4(kp[0], kp[1], kp[2], kp[3]);
    __syncthreads();
    int w = tid >> 6, lane = tid & 63;
    int l15 = lane & 15, lhi = lane >> 4;
    int jw = w << 5;
    s16x8 af[4][2], bfv[2][2];
    #pragma unroll
    for (int fro = 0; fro < 4; ++fro)
        #pragma unroll
        for (int ks = 0; ks < 2; ++ks)
            af[fro][ks] = *(const s16x8*)&Wb[(fro * 16 + l15) * 72 + ks * 32 + lhi * 8];
    #pragma unroll
    for (int fc = 0; fc < 2; ++fc)
        #pragma unroll
        for (int ks = 0; ks < 2; ++ks) {
            int jcol = jw + fc * 16 + l15;
            int cb = ks * 32 + lhi * 8;
            s16x8 t;
            #pragma unroll
            for (int e = 0; e < 8; ++e)
                t[e] = (short)xtb[(cb + e) * 132 + jcol];
            bfv[fc][ks] = t;
        }
    if (tid < 128) {
        float kv = 0.f;
        #pragma unroll
        for (int g8 = 0; g8 < 8; ++g8) kv += kred[g8 * 128 + tid];
        kl[tid] = kv;
        kk_[(size_t)b * 16384 + j0 + tid] = kv;
    }
    __syncthreads();
    f32x4 acc[4][2] = {};
    #pragma unroll
    for (int ks = 0; ks < 2; ++ks)
        #pragma unroll
        for (int fc = 0; fc < 2; ++fc)
            #pragma unroll
            for (int fro = 0; fro < 4; ++fro)
                acc[fro][fc] = __builtin_amdgcn_mfma_f32_16x16x32_bf16(
                    af[fro][ks], bfv[fc][ks], acc[fro][fc], 0, 0, 0);
    if (tid < 128) {
        int ml = tid >> 4, tq = tid & 15;
        float qv = 0.f;
        #pragma unroll
        for (int s = 0; s < 16; ++s) qv = fmaf(kl[ml * 16 + s], wl[s * 17 + tq], qv);
        kq_[(size_t)b * 16384 + j0 + tid] = qv;
    }
    #pragma unroll
    for (int fro = 0; fro < 4; ++fro)
        #pragma unroll
        for (int fc = 0; fc < 2; ++fc) {
            int jl = jw + fc * 16 + l15;
            int o0 = fro * 16 + lhi * 4;
            ushort4 pk = make_ushort4(f2bf(acc[fro][fc][0]), f2bf(acc[fro][fc][1]),
                                      f2bf(acc[fro][fc][2]), f2bf(acc[fro][fc][3]));
            *(ushort4*)&Ys[jl * 72 + o0] = pk;
        }
    __syncthreads();
    unsigned short* dstb = Yt + ((size_t)b << 20) + (size_t)mc * 8192;
    #pragma unroll
    for (int it = 0; it < 4; ++it) {
        int r = it * 256 + tid;
        int o = r >> 4, t = r & 15;
        u16x8 v0;
        #pragma unroll
        for (int q8 = 0; q8 < 8; ++q8) v0[q8] = Ys[(q8 * 16 + t) * 72 + o];
        *(u16x8*)(dstb + (size_t)r * 8) = v0;
    }
}

// ---------------- kBP (unchanged) ----------------
__global__ __launch_bounds__(256) void kBP(const float* __restrict__ kk_,
                                           const float* __restrict__ kq_,
                                           const float* __restrict__ adj,
                                           unsigned short* __restrict__ Pbf) {
    int tid = threadIdx.x;
    int bid = blockIdx.x;
    int wg  = (bid & 7) * 1024 + (bid >> 3);
    int b  = wg >> 8;
    int n0 = (wg & 255) * 4;
    __shared__ float kql[4][16];
    __shared__ float redm[4][4], reds[4][4];
    if (tid < 64)
        kql[tid >> 4][tid & 15] =
            kq_[((size_t)b * 1024 + n0 + (tid >> 4)) * 16 + (tid & 15)];
    __syncthreads();
    const float* kb = kk_ + (size_t)b * 16384;
    float kf[4][16];
    #pragma unroll
    for (int u = 0; u < 4; ++u) {
        const float* p = &kb[(size_t)(u * 256 + tid) * 16];
        #pragma unroll
        for (int s = 0; s < 16; ++s) kf[u][s] = p[s];
    }
    float sc[4][4];
    #pragma unroll
    for (int r = 0; r < 4; ++r)
        #pragma unroll
        for (int u = 0; u < 4; ++u) {
            float a = 0.f;
            #pragma unroll
            for (int s = 0; s < 16; ++s) a = fmaf(kql[r][s], kf[u][s], a);
            sc[r][u] = a;
        }
    float mx[4];
    #pragma unroll
    for (int r = 0; r < 4; ++r)
        mx[r] = fmaxf(fmaxf(sc[r][0], sc[r][1]), fmaxf(sc[r][2], sc[r][3]));
    #pragma unroll
    for (int off = 32; off; off >>= 1)
        #pragma unroll
        for (int r = 0; r < 4; ++r) mx[r] = fmaxf(mx[r], __shfl_xor(mx[r], off));
    int w = tid >> 6;
    if ((tid & 63) == 0)
        #pragma unroll
        for (int r = 0; r < 4; ++r) redm[w][r] = mx[r];
    __syncthreads();
    #pragma unroll
    for (int r = 0; r < 4; ++r)
        mx[r] = fmaxf(fmaxf(redm[0][r], redm[1][r]), fmaxf(redm[2][r], redm[3][r]));
    float e[4][4], se[4];
    #pragma unroll
    for (int r = 0; r < 4; ++r) {
        float s = 0.f;
        #pragma unroll
        for (int u = 0; u < 4; ++u) { e[r][u] = __expf(sc[r][u] - mx[r]); s += e[r][u]; }
        se[r] = s;
    }
    #pragma unroll
    for (int off = 32; off; off >>= 1)
        #pragma unroll
        for (int r = 0; r < 4; ++r) se[r] += __shfl_xor(se[r], off);
    if ((tid & 63) == 0)
        #pragma unroll
        for (int r = 0; r < 4; ++r) reds[w][r] = se[r];
    __syncthreads();
    float rrs[4];
    #pragma unroll
    for (int r = 0; r < 4; ++r)
        rrs[r] = 1.f / (reds[0][r] + reds[1][r] + reds[2][r] + reds[3][r]);
    #pragma unroll
    for (int r = 0; r < 4; ++r)
        #pragma unroll
        for (int u = 0; u < 4; ++u) {
            size_t m = (size_t)u * 256 + tid;
            float av = adj[(size_t)(n0 + r) * 1024 + m];
            Pbf[((size_t)b * 1024 + n0 + r) * 1024 + m] = f2bf(e[r][u] * rrs[r] * av);
        }
}

// ---------------- kD: counted-vmcnt staging + phase-ahead af pipeline -------
static __device__ __forceinline__ void stage_tile(const unsigned short* Pb,
                                                  const unsigned short* Yb,
                                                  unsigned short* lds, int buf,
                                                  int kt, int ww, int l) {
    int r8  = (l >> 3) & 7;
    int cs  = (l & 7) ^ r8;
    int glc = cs << 3;
    int k0  = kt << 6;
    unsigned short* base = lds + buf * 32768;
    #pragma unroll
    for (int s = 0; s < 4; ++s) {
        int row = s * 64 + ww * 8;
        size_t ga = ((size_t)(row + r8) << 10) + k0 + glc;
        GLOAD_LDS16(Pb + ga, base + row * 64);
        size_t gb = (size_t)(kt * 8 + cs) * 8192 + (size_t)(row + r8) * 8;
        GLOAD_LDS16(Yb + gb, base + 16384 + row * 64);
    }
}

static __device__ __forceinline__ s16x8 frag_ld(const unsigned short* base,
                                                int R, int kc, int l7) {
    return *(const s16x8*)(base + R * 64 + ((kc ^ l7) << 3));
}

#define READ_AF(dst, qq)                                                       \
    _Pragma("unroll")                                                          \
    for (int mi = 0; mi < 2; ++mi)                                             \
        _Pragma("unroll")                                                      \
        for (int ks = 0; ks < 2; ++ks)                                         \
            dst[mi][ks] = frag_ld(Ab, wr * 128 + ((qq) * 2 + mi) * 16 + l15,   \
                                  ks * 4 + lhi, l7);

#define MFMA16(src, qq)                                                        \
    _Pragma("unroll")                                                          \
    for (int mi = 0; mi < 2; ++mi)                                             \
        _Pragma("unroll")                                                      \
        for (int nj = 0; nj < 4; ++nj)                                         \
            _Pragma("unroll")                                                  \
            for (int ks = 0; ks < 2; ++ks)                                     \
                acc[(qq) * 2 + mi][nj] = __builtin_amdgcn_mfma_f32_16x16x32_bf16( \
                    src[mi][ks], bf[nj][ks], acc[(qq) * 2 + mi][nj], 0, 0, 0);

__global__ __launch_bounds__(512, 2) void kD(const unsigned short* __restrict__ P,
                                             const unsigned short* __restrict__ Yt,
                                             float* __restrict__ out) {
    extern __shared__ unsigned short lds[];   // 2 bufs x 64 KB = 128 KiB
    int bid = blockIdx.x;
    int wg  = (bid & 7) * 64 + (bid >> 3);    // XCD-grouped
    int b   = wg >> 4;
    int rem = wg & 15;
    int n0  = (rem & 3) << 8;
    int j0  = (rem >> 2) << 8;
    int tid = threadIdx.x;
    int l = tid & 63, ww = tid >> 6;
    int wr = ww >> 2, wc = ww & 3;
    int l15 = l & 15, lhi = l >> 4, l7 = l & 7;
    const unsigned short* Pb = P  + ((size_t)b << 20) + ((size_t)n0 << 10);
    const unsigned short* Yb = Yt + ((size_t)b << 20) + (size_t)j0 * 8;

    f32x4 acc[8][4] = {};
    stage_tile(Pb, Yb, lds, 0, 0, ww, l);

    for (int kt = 0; kt < 16; ++kt) {
        int cur = kt & 1;
        const unsigned short* Ab = lds + cur * 32768;
        const unsigned short* Bb = Ab + 16384;
        if (kt < 15) {
            stage_tile(Pb, Yb, lds, cur ^ 1, kt + 1, ww, l);
            asm volatile("s_waitcnt vmcnt(8)" ::: "memory");
        } else {
            asm volatile("s_waitcnt vmcnt(0)" ::: "memory");
        }
        __builtin_amdgcn_s_barrier();        // tile kt resident in buf[cur]
        __builtin_amdgcn_sched_barrier(0);
        // issue bf (8) + af q0 (4)
        s16x8 bf[4][2], afA[2][2], afB[2][2];
        #pragma unroll
        for (int nj = 0; nj < 4; ++nj)
            #pragma unroll
            for (int ks = 0; ks < 2; ++ks)
                bf[nj][ks] = frag_ld(Bb, wc * 64 + nj * 16 + l15, ks * 4 + lhi, l7);
        READ_AF(afA, 0)
        // q0: issue af(q1); wait bf+af(q0); MFMA q0
        READ_AF(afB, 1)
        asm volatile("s_waitcnt lgkmcnt(4)" ::: "memory");
        __builtin_amdgcn_sched_barrier(0);
        __builtin_amdgcn_s_setprio(1);
        MFMA16(afA, 0)
        __builtin_amdgcn_s_setprio(0);
        __builtin_amdgcn_s_barrier();
        // q1: issue af(q2); wait af(q1); MFMA q1
        READ_AF(afA, 2)
        asm volatile("s_waitcnt lgkmcnt(4)" ::: "memory");
        __builtin_amdgcn_sched_barrier(0);
        __builtin_amdgcn_s_setprio(1);
        MFMA16(afB, 1)
        __builtin_amdgcn_s_setprio(0);
        __builtin_amdgcn_s_barrier();
        // q2: issue af(q3); wait af(q2); MFMA q2
        READ_AF(afB, 3)
        asm volatile("s_waitcnt lgkmcnt(4)" ::: "memory");
        __builtin_amdgcn_sched_barrier(0);
        __builtin_amdgcn_s_setprio(1);
        MFMA16(afA, 2)
        __builtin_amdgcn_s_setprio(0);
        __builtin_amdgcn_s_barrier();
        // q3: wait af(q3); MFMA q3
        asm volatile("s_waitcnt lgkmcnt(0)" ::: "memory");
        __builtin_amdgcn_sched_barrier(0);
        __builtin_amdgcn_s_setprio(1);
        MFMA16(afB, 3)
        __builtin_amdgcn_s_setprio(0);
        __builtin_amdgcn_s_barrier();        // tile end (buf[cur] free for reuse)
    }

    #pragma unroll
    for (int mi = 0; mi < 8; ++mi)
        #pragma unroll
        for (int nj = 0; nj < 4; ++nj) {
            int o  = (j0 >> 4) + wc * 4 + nj;
            int nb = n0 + wr * 128 + mi * 16 + lhi * 4;
            float* op = out + ((size_t)(b * 64 + o) << 14) + (size_t)nb * 16 + l15;
            #pragma unroll
            for (int q = 0; q < 4; ++q) op[q * 16] = acc[mi][nj][q];
        }
}

extern "C" void kernel_launch(void* const* d_in, const int* in_sizes, int n_in,
                              void* d_out, int out_size, void* d_ws, size_t ws_size,
                              hipStream_t stream) {
    const float* x     = (const float*)d_in[0];
    const float* adj   = (const float*)d_in[1];
    const float* alpha = (const float*)d_in[2];
    const float* Watt  = (const float*)d_in[3];
    const float* Wout  = (const float*)d_in[4];
    float* out = (float*)d_out;

    char* ws = (char*)d_ws;
    float* k  = (float*)ws;                                            // 2 MB
    float* kq = (float*)(ws + 2097152);                                // 2 MB
    unsigned short* Pbf = (unsigned short*)(ws + 4194304);             // 64 MB
    unsigned short* Yt  = (unsigned short*)(ws + 4194304 + 67108864);  // 64 MB

    kCM<<<4096, 256, 33600, stream>>>(x, Wout, alpha, Watt, Yt, k, kq);
    kBP<<<8192, 256, 0, stream>>>(k, kq, adj, Pbf);
    kD <<<512, 512, 131072, stream>>>(Pbf, Yt, out);
}